// Round 11
// baseline (83.637 us; speedup 1.0000x reference)
//
#include <hip/hip_runtime.h>

// DAA autoencoder, FUSED single kernel.
//   layer0: h[b][o]   = min_i ( sel0[o][i] ? x[b][i] : 2.0f )   (t-norm)
//   layer1: out[b][o] = max_i ( sel1[o][i] ? h[b][i] : -1.0f )  (t-conorm)
// B=256, IN=1024, HID=512.
//
// R10 lesson: compute explains only ~9 us of 25.3 -> the fat is the
// 3-dependent-dispatch structure (ramp/drain/idle bubbles). R11 fuses
// pack + L0 + L1 into one 256-block x 1024-thr kernel (1 block/CU,
// co-resident by construction: 32KB LDS, <=128 VGPR) with device-scope
// atomic grid barriers (G16: __threadfence + AGENT atomics). Barrier
// counters in d_ws, zeroed via hipMemsetAsync each launch (graph-safe,
// deterministic). Phase bodies identical to R10 (bit-exact, absmax 0.0).

#define NB 256

// ---- one-shot device-scope grid barrier (counter pre-zeroed per launch) --
__device__ __forceinline__ void gridbar(unsigned* cnt, unsigned target) {
    __syncthreads();
    if (threadIdx.x == 0) {
        __threadfence();   // device-scope release of this block's writes
        __hip_atomic_fetch_add(cnt, 1u, __ATOMIC_ACQ_REL,
                               __HIP_MEMORY_SCOPE_AGENT);
        while (__hip_atomic_load(cnt, __ATOMIC_ACQUIRE,
                                 __HIP_MEMORY_SCOPE_AGENT) < target)
            __builtin_amdgcn_s_sleep(2);
    }
    __syncthreads();
}

// ---- masked min/max layer phase (R10's daa_layer body) -------------------
// OT=8: rows o0..o0+3 staged in LDS (ds broadcast), rows o0+4..o0+7 read
// from pre-expanded global addends agh (scalar s_load path).
template<int INF, bool ISMIN, bool TOUT>
__device__ __forceinline__ void daa_phase(
    const float4* __restrict__ inT4,   // [INF/4][NB]
    const int*    __restrict__ sel,    // [OUTF][INF]
    const float4* __restrict__ agh,    // pre-expanded rows (o&7)>=4
    float* __restrict__ out, int OUTF, int vblk, float4* uni)
{
    constexpr int S  = 16;
    constexpr int C4 = INF / 4 / S;
    constexpr int R4 = INF / 4;
    const int tid  = threadIdx.x;
    const int lane = tid & 63;
    const int s    = __builtin_amdgcn_readfirstlane(tid >> 6);
    const int bch  = vblk & 3;
    const int o0   = (vblk >> 2) * 8;
    const int b    = bch * 64 + lane;
    const float off = ISMIN ? 2.0f : -1.0f;
    const float inf = ISMIN ? __builtin_inff() : -__builtin_inff();

    __syncthreads();   // uni may still be read by caller's previous phase
    if (tid < 4 * R4) {
        const int4 v = ((const int4*)sel)[(size_t)o0 * R4 + tid];
        uni[tid] = make_float4(v.x ? 0.f : inf, v.y ? 0.f : inf,
                               v.z ? 0.f : inf, v.w ? 0.f : inf);
    }
    __syncthreads();

    float acc[8];
#pragma unroll
    for (int u = 0; u < 8; ++u) acc[u] = off;

    const float4* __restrict__ xp = inT4 + (size_t)(s * C4) * NB + b;
    const float4* __restrict__ aL = uni + s * C4;
    const float4* __restrict__ aG = agh + ((size_t)(o0 >> 3) * 4) * R4 + s * C4;

#define MM(A, X, AV)                                                   \
    do {                                                               \
        if (ISMIN) {                                                   \
            A = fminf(fminf(A, (X).x + (AV).x), (X).y + (AV).y);       \
            A = fminf(fminf(A, (X).z + (AV).z), (X).w + (AV).w);       \
        } else {                                                       \
            A = fmaxf(fmaxf(A, (X).x + (AV).x), (X).y + (AV).y);       \
            A = fmaxf(fmaxf(A, (X).z + (AV).z), (X).w + (AV).w);       \
        }                                                              \
    } while (0)

    float4 xa = xp[0];
    for (int c = 0; c < C4; ++c) {
        float4 nx = xa;
        if (c + 1 < C4) nx = xp[(size_t)(c + 1) * NB];
#pragma unroll
        for (int u = 0; u < 4; ++u) {       // LDS broadcast path
            const float4 av = aL[u * R4 + c];
            MM(acc[u], xa, av);
        }
#pragma unroll
        for (int u = 0; u < 4; ++u) {       // scalar s_load path
            const float4 av = aG[u * R4 + c];
            MM(acc[4 + u], xa, av);
        }
        xa = nx;
    }
#undef MM

    __syncthreads();                    // addend-LDS reads complete
    float* redf = (float*)uni;          // red[16][8][64] floats (32 KB)
#pragma unroll
    for (int u = 0; u < 8; ++u) redf[(s * 8 + u) * 64 + lane] = acc[u];
    __syncthreads();

    if (tid < 512) {                    // merge 16 partials per (u, lane)
        const int u = tid >> 6, ln = tid & 63;
        float v = redf[u * 64 + ln];
#pragma unroll
        for (int ss = 1; ss < S; ++ss) {
            const float q = redf[(ss * 8 + u) * 64 + ln];
            v = ISMIN ? fminf(v, q) : fmaxf(v, q);
        }
        redf[u * 64 + ln] = v;          // slot (0,u,ln): owner-only
    }
    __syncthreads();

    if (tid < 64) {                     // coalesced float4 stores
        const int bb = bch * 64 + tid;
        const float4 lo = make_float4(redf[0 * 64 + tid], redf[1 * 64 + tid],
                                      redf[2 * 64 + tid], redf[3 * 64 + tid]);
        const float4 hi = make_float4(redf[4 * 64 + tid], redf[5 * 64 + tid],
                                      redf[6 * 64 + tid], redf[7 * 64 + tid]);
        if (TOUT) {
            ((float4*)out)[(size_t)(o0 >> 2) * NB + bb]       = lo;
            ((float4*)out)[((size_t)(o0 >> 2) + 1) * NB + bb] = hi;
        } else {
            float4* p = (float4*)(out + (size_t)bb * OUTF + o0);
            p[0] = lo; p[1] = hi;
        }
    }
}

// ---- the fused kernel ----------------------------------------------------
__global__ __launch_bounds__(1024, 4) void daa_fused(
    const float* __restrict__ x,
    const int*   __restrict__ sel0, const int* __restrict__ sel1,
    float4* __restrict__ xT4, float* __restrict__ hT,
    float4* __restrict__ a0h, float4* __restrict__ a1h,
    unsigned* __restrict__ bars, float* __restrict__ out)
{
    __shared__ float4 uni[2048];        // 32 KB, time-shared across phases
    const int blk = blockIdx.x, tid = threadIdx.x;
    const unsigned nblk = gridDim.x;

    // ---- phase 0a: expand scalar-path sel halves (1 float4 per thread) ---
    {
        const int g = blk * 1024 + tid;             // 262144 threads
        const float pinf = __builtin_inff();
        if (g < 65536) {                            // a0h: [256 rows][256 f4]
            const int j = g >> 8, i4 = g & 255;
            const int srow = (j >> 2) * 8 + 4 + (j & 3);
            const int4 v = ((const int4*)sel0)[srow * 256 + i4];
            a0h[g] = make_float4(v.x ? 0.f : pinf, v.y ? 0.f : pinf,
                                 v.z ? 0.f : pinf, v.w ? 0.f : pinf);
        } else if (g < 131072) {                    // a1h: [512 rows][128 f4]
            const int t4 = g - 65536;
            const int j = t4 >> 7, i4 = t4 & 127;
            const int srow = (j >> 2) * 8 + 4 + (j & 3);
            const int4 v = ((const int4*)sel1)[srow * 128 + i4];
            a1h[t4] = make_float4(v.x ? 0.f : -pinf, v.y ? 0.f : -pinf,
                                  v.z ? 0.f : -pinf, v.w ? 0.f : -pinf);
        }
    }

    // ---- phase 0b: transpose quarter-tile (64 i x 16 b per block) --------
    {
        float* tmp = (float*)uni;                   // [16][65]
        const int i0 = (blk & 15) * 64, b0 = (blk >> 4) * 16;
        const int r = tid >> 6, c = tid & 63;
        tmp[r * 65 + c] = x[(size_t)(b0 + r) * 1024 + i0 + c];
        __syncthreads();
        if (tid < 256) {
            const int i4 = tid >> 4, bb = tid & 15;
            xT4[(size_t)(i0 / 4 + i4) * NB + b0 + bb] =
                make_float4(tmp[bb * 65 + 4 * i4 + 0],
                            tmp[bb * 65 + 4 * i4 + 1],
                            tmp[bb * 65 + 4 * i4 + 2],
                            tmp[bb * 65 + 4 * i4 + 3]);
        }
    }

    gridbar(bars + 0, nblk);

    // ---- phase 1: layer 0 (min), vblk = blk ------------------------------
    daa_phase<1024, true, true>(xT4, sel0, a0h, hT, 512, blk, uni);

    gridbar(bars + 32, nblk);           // separate cache line

    // ---- phase 2: layer 1 (max), 512 virtual blocks, 2 per real block ----
    daa_phase<512, false, false>((const float4*)hT, sel1, a1h, out, 1024,
                                 2 * blk + 0, uni);
    daa_phase<512, false, false>((const float4*)hT, sel1, a1h, out, 1024,
                                 2 * blk + 1, uni);
}

extern "C" void kernel_launch(void* const* d_in, const int* in_sizes, int n_in,
                              void* d_out, int out_size, void* d_ws, size_t ws_size,
                              hipStream_t stream) {
    const float* x    = (const float*)d_in[0];  // [256,1024] f32
    const int*   sel0 = (const int*)d_in[1];    // [512,1024] i32
    const int*   sel1 = (const int*)d_in[2];    // [1024,512] i32
    float* out = (float*)d_out;                 // [256,1024] f32

    char* ws = (char*)d_ws;
    float4*   xT4  = (float4*)ws;                       // 1 MB
    float*    hT   = (float*)(ws + (1 << 20));          // 0.5 MB
    float4*   a0h  = (float4*)(ws + 3 * (1 << 19));     // 1 MB @1.5MB
    float4*   a1h  = (float4*)(ws + 5 * (1 << 19));     // 1 MB @2.5MB
    unsigned* bars = (unsigned*)(ws + (4 << 20));       // counters @4MB

    // zero the barrier counters (graph-safe, deterministic every launch)
    hipMemsetAsync(bars, 0, 256, stream);

    // one fused kernel: 256 blocks (1/CU, co-resident), 1024 threads
    daa_fused<<<256, 1024, 0, stream>>>(x, sel0, sel1, xT4, hT, a0h, a1h,
                                        bars, out);
}

// Round 12
// 61.325 us; speedup vs baseline: 1.3638x; 1.3638x over previous
//
#include <hip/hip_runtime.h>

// DAA autoencoder — probe-after-sort algorithm (R12).
//   layer0: h[b][o]   = min_i ( sel0[o][i] ? x[b][i] : 2.0f )
//   layer1: out[b][o] = max_i ( sel1[o][i] ? h[b][i] : -1.0f )
// B=256, IN=1024, HID=512.
//
// Key identity: min over a selected subset == FIRST element of the
// ascending-sorted row whose index is selected (expected ~2 probes at
// density 1/2); max == first of the descending-sorted row. No FP
// arithmetic is performed anywhere (sorts compare bit patterns — all
// values >= 0 so float order == uint order; probes only select), so the
// result is bit-exact vs the reference. All-deselected rows fall through
// the full stream and return the offset (2.0 / -1.0) exactly.
//
// R11 lesson: grid-barrier fusion = 3x regression (device-scope fences
// nuke per-XCD L2); R2 evidence: inter-kernel gap in graph replay ~= 0.
// So: 5 small kernels, no atomics, no fences.

typedef unsigned long long u64;
typedef unsigned u32;

// ---- K1: ballot-pack sel -> bit-transposed masks mT[i>>5][o] -------------
__global__ __launch_bounds__(256) void build_masks(
    const int* __restrict__ sel0, const int* __restrict__ sel1,
    u32* __restrict__ mT0,   // [32][512]
    u32* __restrict__ mT1)   // [16][1024]
{
    const int tid  = threadIdx.x;
    const int lane = tid & 63;
    const int gw   = blockIdx.x * 4 + (tid >> 6);   // wave id 0..1023
#pragma unroll 1
    for (int m = 0; m < 16; ++m) {
        const int task = gw * 16 + m;               // 16384 tasks total
        if (task < 8192) {                          // mask0: o<512, seg<16
            const int o = task >> 4, seg = task & 15;
            const int v = sel0[o * 1024 + seg * 64 + lane];
            const u64 bal = __ballot(v != 0);       // bit j <-> i = seg*64+j
            if (lane == 0) {
                mT0[(seg * 2 + 0) * 512 + o] = (u32)bal;
                mT0[(seg * 2 + 1) * 512 + o] = (u32)(bal >> 32);
            }
        } else {                                    // mask1: o<1024, seg<8
            const int t2 = task - 8192;
            const int o = t2 >> 3, seg = t2 & 7;
            const int v = sel1[o * 512 + seg * 64 + lane];
            const u64 bal = __ballot(v != 0);
            if (lane == 0) {
                mT1[(seg * 2 + 0) * 1024 + o] = (u32)bal;
                mT1[(seg * 2 + 1) * 1024 + o] = (u32)(bal >> 32);
            }
        }
    }
}

// ---- K2: per-row ascending bitonic sort of x (keys = valbits<<32 | idx) --
__global__ __launch_bounds__(512) void sort_x(
    const float* __restrict__ x, u64* __restrict__ S0)   // S0 [256][1024]
{
    __shared__ u64 key[1024];
    const int b = blockIdx.x, tid = threadIdx.x;
    key[tid]       = ((u64)__float_as_uint(x[b * 1024 + tid]) << 32) | (u32)tid;
    key[tid + 512] = ((u64)__float_as_uint(x[b * 1024 + tid + 512]) << 32)
                     | (u32)(tid + 512);
    for (int k = 2; k <= 1024; k <<= 1)
        for (int j = k >> 1; j > 0; j >>= 1) {
            __syncthreads();
#pragma unroll 1
            for (int t = tid; t < 1024; t += 512) {
                const int l = t ^ j;
                if (l > t) {
                    const u64 a = key[t], c = key[l];
                    if (((t & k) == 0) ? (a > c) : (a < c)) {
                        key[t] = c; key[l] = a;
                    }
                }
            }
        }
    __syncthreads();
    S0[b * 1024 + tid]       = key[tid];
    S0[b * 1024 + tid + 512] = key[tid + 512];
}

// ---- K3: probe layer 0 (min): first sorted index hitting the mask --------
__global__ __launch_bounds__(512) void probe_min(
    const u64* __restrict__ S0, const u32* __restrict__ mT0,
    float* __restrict__ h)                              // h [256][512]
{
    __shared__ __align__(16) u32 msk[32 * 512];         // 64 KB slab
    const int tid = threadIdx.x;
#pragma unroll
    for (int q = 0; q < 8; ++q)                         // 4096 uint4, coalesced
        ((uint4*)msk)[q * 512 + tid] = ((const uint4*)mT0)[q * 512 + tid];
    __syncthreads();

    const int b0 = blockIdx.x * 2;
#pragma unroll 1
    for (int bb = 0; bb < 2; ++bb) {
        const int b = b0 + bb;
        const u64* __restrict__ st = S0 + b * 1024;     // uniform -> s_load
        float hv = 2.0f;
        bool found = false;
        int k = 0;
        while (true) {
#pragma unroll
            for (int q = 0; q < 8; ++q) {
                const u64 key = st[k + q];
                const u32 i   = (u32)key;
                const float v = __uint_as_float((u32)(key >> 32));
                const u32 m   = msk[(i >> 5) * 512 + tid];  // lane-consec o
                if (!found && ((m >> (i & 31)) & 1u)) { hv = v; found = true; }
            }
            k += 8;
            if (__all(found) || k == 1024) break;
        }
        h[b * 512 + tid] = hv;                          // coalesced
    }
}

// ---- K4: per-row DESCENDING bitonic sort of h ----------------------------
__global__ __launch_bounds__(256) void sort_h(
    const float* __restrict__ h, u64* __restrict__ S1)  // S1 [256][512]
{
    __shared__ u64 key[512];
    const int b = blockIdx.x, tid = threadIdx.x;
    key[tid]       = ((u64)__float_as_uint(h[b * 512 + tid]) << 32) | (u32)tid;
    key[tid + 256] = ((u64)__float_as_uint(h[b * 512 + tid + 256]) << 32)
                     | (u32)(tid + 256);
    for (int k = 2; k <= 512; k <<= 1)
        for (int j = k >> 1; j > 0; j >>= 1) {
            __syncthreads();
#pragma unroll 1
            for (int t = tid; t < 512; t += 256) {
                const int l = t ^ j;
                if (l > t) {
                    const u64 a = key[t], c = key[l];
                    if (((t & k) == 0) ? (a < c) : (a > c)) {   // descending
                        key[t] = c; key[l] = a;
                    }
                }
            }
        }
    __syncthreads();
    S1[b * 512 + tid]       = key[tid];
    S1[b * 512 + tid + 256] = key[tid + 256];
}

// ---- K5: probe layer 1 (max): first descending index hitting the mask ----
__global__ __launch_bounds__(512) void probe_max(
    const u64* __restrict__ S1, const u32* __restrict__ mT1,
    float* __restrict__ out)                            // out [256][1024]
{
    __shared__ __align__(16) u32 msk[16 * 512];         // 32 KB slab
    const int tid = threadIdx.x;
    const int og  = blockIdx.x & 1;                     // o-half
#pragma unroll
    for (int c = 0; c < 16; ++c)
        msk[c * 512 + tid] = mT1[c * 1024 + og * 512 + tid];
    __syncthreads();

    const int b0 = (blockIdx.x >> 1) * 2;
#pragma unroll 1
    for (int bb = 0; bb < 2; ++bb) {
        const int b = b0 + bb;
        const u64* __restrict__ st = S1 + b * 512;      // uniform -> s_load
        float ov = -1.0f;
        bool found = false;
        int k = 0;
        while (true) {
#pragma unroll
            for (int q = 0; q < 8; ++q) {
                const u64 key = st[k + q];
                const u32 i   = (u32)key;               // h-index, < 512
                const float v = __uint_as_float((u32)(key >> 32));
                const u32 m   = msk[(i >> 5) * 512 + tid];
                if (!found && ((m >> (i & 31)) & 1u)) { ov = v; found = true; }
            }
            k += 8;
            if (__all(found) || k == 512) break;
        }
        out[b * 1024 + og * 512 + tid] = ov;            // coalesced
    }
}

extern "C" void kernel_launch(void* const* d_in, const int* in_sizes, int n_in,
                              void* d_out, int out_size, void* d_ws, size_t ws_size,
                              hipStream_t stream) {
    const float* x    = (const float*)d_in[0];  // [256,1024] f32
    const int*   sel0 = (const int*)d_in[1];    // [512,1024] i32
    const int*   sel1 = (const int*)d_in[2];    // [1024,512] i32
    float* out = (float*)d_out;                 // [256,1024] f32

    char* ws = (char*)d_ws;
    u32* mT0 = (u32*)ws;                                    // 64 KB
    u32* mT1 = (u32*)(ws + 65536);                          // 64 KB
    u64* S0  = (u64*)(ws + 131072);                         // 2 MB
    u64* S1  = (u64*)(ws + 131072 + (1 << 21));             // 1 MB
    float* h = (float*)(ws + 131072 + (1 << 21) + (1 << 20)); // 512 KB

    build_masks<<<256, 256, 0, stream>>>(sel0, sel1, mT0, mT1);
    sort_x<<<256, 512, 0, stream>>>(x, S0);
    probe_min<<<128, 512, 0, stream>>>(S0, mT0, h);
    sort_h<<<256, 256, 0, stream>>>(h, S1);
    probe_max<<<256, 512, 0, stream>>>(S1, mT1, out);
}